// Round 7
// baseline (311.406 us; speedup 1.0000x reference)
//
#include <hip/hip_runtime.h>
#include <math.h>

#define NF 40
#define FS 401
#define AST 424            // A row stride (f16), 848B, 16B-aligned rows
#define PSTRIDE 160
#define BB 8
#define LL 160000
#define PADL 256
#define PADR 512
#define LST 160768         // PADL + LL + PADR
#define TOUT 1000
#define NTILE 256          // conv positions per block (4 waves x 64)
#define NCHUNKC 625        // 625*256 = 160000 exact
#define ROWCH 89           // slab chunks per row; 89 % 8 == 1 -> conflict-free phases
#define ROWST (ROWCH*8)    // 712 f16 per row
#define TCP 16             // frames per pool block
#define NCHUNKP 63
#define NCONVB 5024        // BB*LST/256 exactly

typedef __attribute__((ext_vector_type(8))) _Float16 half8v;
typedef __attribute__((ext_vector_type(4))) _Float16 half4v;
typedef __attribute__((ext_vector_type(4))) float float4v;
typedef _Float16 f16;

__device__ __forceinline__ float sigm(float x) { return 1.0f / (1.0f + __expf(-x)); }
__device__ __forceinline__ float tanh_fast(float x) { return 1.0f - 2.0f / (__expf(2.0f * x) + 1.0f); }

// ---------- prep (single dispatch): x->f16 padded, and Gabor filters ----------
__global__ __launch_bounds__(256) void prep_all(
    const float* __restrict__ x, const float* __restrict__ cf_,
    const float* __restrict__ bw_, f16* __restrict__ xb, f16* __restrict__ Ag)
{
    int blk = blockIdx.x;
    if (blk < NCONVB) {
        int i = blk * 256 + threadIdx.x;
        int b = i / LST, o = i % LST;
        float v = 0.0f;
        if (o >= PADL && o < PADL + LL) v = x[b * LL + (o - PADL)];
        xb[i] = (f16)v;
        return;
    }
    const float PI_F = 3.14159265358979323846f;
    int row = blk - NCONVB;         // 0..79
    int f = row >> 1, comp = row & 1;
    float Z = sqrtf(2.0f * logf(2.0f)) / PI_F;
    float cf = fminf(fmaxf(cf_[f], 0.0f), PI_F);
    float bw = fminf(fmaxf(bw_[f], 4.0f * Z), 401.0f * Z);
    float denom = 1.0f / (sqrtf(2.0f * PI_F) * bw);
    float inv2 = 1.0f / (2.0f * bw * bw);
    for (int k = threadIdx.x; k < AST; k += 256) {
        float v = 0.0f;
        if (k < FS) {
            float t = (float)(k - 200);
            float g = denom * expf(-(t * t) * inv2);
            float sv, cv;
            sincosf(cf * t, &sv, &cv);
            v = comp ? g * sv : g * cv;
        }
        Ag[row * AST + k] = (f16)v;
    }
}

// ---------- conv via MFMA: 8-shifted-row slab + Toeplitz B-frag rotation ----------
// F(s,k+32) = F(s+2,k): per unrolled K-step only 2 fresh ds_read_b128 (s=4,5),
// tiles s=0..3 rotate in registers.
__global__ __launch_bounds__(256, 3) void conv_mfma(
    const f16* __restrict__ xb,    // padded [nb][LST]
    const f16* __restrict__ Ag,    // [80][AST]
    f16* __restrict__ eb)          // [nb][NF][LL]
{
    __shared__ f16 slab[8 * ROWST];           // 11392 B
    int chunk = blockIdx.x;
    int bi = blockIdx.y;
    int p0 = chunk * NTILE;
    int pbase = PADL + p0 - 200;              // ≡ 0 (mod 8)
    const f16* xs = xb + (size_t)bi * LST;
    int tid = threadIdx.x;

    for (int sc = tid; sc < 8 * ROWCH; sc += 256) {
        int r = sc / ROWCH, m = sc - r * ROWCH;
        int s0 = pbase + 8 * m + (r & ~1);
        const uint* gp = (const uint*)(xs + s0);
        uint v0 = gp[0], v1 = gp[1], v2 = gp[2], v3 = gp[3], v4 = gp[4];
        if (r & 1) {
            v0 = __builtin_amdgcn_alignbyte(v1, v0, 2);
            v1 = __builtin_amdgcn_alignbyte(v2, v1, 2);
            v2 = __builtin_amdgcn_alignbyte(v3, v2, 2);
            v3 = __builtin_amdgcn_alignbyte(v4, v3, 2);
        }
        *(uint4*)(&slab[r * ROWST + 8 * m]) = make_uint4(v0, v1, v2, v3);
    }
    __syncthreads();

    int wv = tid >> 6, lane = tid & 63, q = lane >> 4, l15 = lane & 15;

    float4v acc[5][4];
#pragma unroll
    for (int t = 0; t < 5; ++t)
#pragma unroll
        for (int s = 0; s < 4; ++s)
            acc[t][s] = (float4v){0.f, 0.f, 0.f, 0.f};

    const f16* aP[5];
    const f16* bPtr[6];
#pragma unroll
    for (int t = 0; t < 5; ++t) aP[t] = Ag + (16 * t + l15) * AST + 8 * q;
#pragma unroll
    for (int s = 0; s < 6; ++s) {
        int pos = 64 * wv + 16 * s + l15;     // up to 64*3+80+15 = 287 (s=5)
        bPtr[s] = slab + (pos & 7) * ROWST + 8 * ((pos >> 3) + q);
    }

    half8v bf[4];
#pragma unroll
    for (int s = 0; s < 4; ++s) bf[s] = *(const half8v*)(bPtr[s]);

#pragma unroll
    for (int kk = 0; kk < 13; ++kk) {
        int k = 32 * kk;
        half8v af[5];
#pragma unroll
        for (int t = 0; t < 5; ++t) af[t] = *(const half8v*)(aP[t] + k);
        half8v nb0, nb1;
        if (kk < 12) {
            nb0 = *(const half8v*)(bPtr[4] + k);
            nb1 = *(const half8v*)(bPtr[5] + k);
        }
#pragma unroll
        for (int t = 0; t < 5; ++t)
#pragma unroll
            for (int s = 0; s < 4; ++s)
                acc[t][s] = __builtin_amdgcn_mfma_f32_16x16x32_f16(af[t], bf[s], acc[t][s], 0, 0, 0);
        if (kk < 12) { bf[0] = bf[2]; bf[1] = bf[3]; bf[2] = nb0; bf[3] = nb1; }
    }

    f16* ebb = eb + (size_t)bi * NF * LL;
#pragma unroll
    for (int t = 0; t < 5; ++t) {
        int f0 = 8 * t + 2 * q;
#pragma unroll
        for (int s = 0; s < 4; ++s) {
            float4v a = acc[t][s];
            int p = p0 + 64 * wv + 16 * s + l15;
            ebb[f0 * LL + p] = (f16)(a.x * a.x + a.y * a.y);
            ebb[(f0 + 1) * LL + p] = (f16)(a.z * a.z + a.w * a.w);
        }
    }
}

// ---------- Gaussian pooling: X[bi][f][tau] ----------
__global__ __launch_bounds__(256) void pool_kernel(
    const f16* __restrict__ eb, const float* __restrict__ pw_, float* __restrict__ Xout)
{
    __shared__ float ys[2816];
    __shared__ float win[416];
    int chunk = blockIdx.x;
    int f = blockIdx.y;
    int bi = blockIdx.z;
    int tau0 = chunk * TCP;
    int start = tau0 * PSTRIDE - 200;
    int tid = threadIdx.x;

    float pw = fminf(fmaxf(pw_[f], 2.0f / 401.0f), 0.5f);
    float invpw = 1.0f / pw;
    for (int k = tid; k < 416; k += 256) {
        float w = 0.0f;
        if (k < FS) {
            float tt = (float)k * (1.0f / 400.0f) - 0.5f;
            float u = tt * invpw;
            w = expf(-0.5f * u * u);
        }
        win[k] = w;
    }
    const f16* erow = eb + ((size_t)bi * NF + f) * LL;
    if (start >= 0 && start + 2816 <= LL) {
        for (int j = tid; j < 352; j += 256) {
            half8v v = *(const half8v*)(erow + start + 8 * j);
#pragma unroll
            for (int i = 0; i < 8; ++i) ys[8 * j + i] = (float)v[i];
        }
    } else {
        for (int j = tid; j < 2816; j += 256) {
            int p = start + j;
            ys[j] = (p >= 0 && p < LL) ? (float)erow[p] : 0.0f;
        }
    }
    __syncthreads();

    int ft = tid >> 4, l16 = tid & 15;
    float acc = 0.0f;
    int yo = ft * PSTRIDE;
    for (int kw = l16; kw < FS; kw += 16)
        acc += ys[yo + kw] * win[kw];
#pragma unroll
    for (int off = 8; off > 0; off >>= 1)
        acc += __shfl_down(acc, off, 16);
    int tau = tau0 + ft;
    if (l16 == 0 && tau < TOUT)
        Xout[((size_t)bi * NF + f) * TOUT + tau] = acc;
}

// ---------- PCEN smoother M via wave-per-bin decayed scan ----------
__global__ __launch_bounds__(256) void pcen_scan_kernel(
    const float* __restrict__ X, float* __restrict__ M)
{
    int wid = (blockIdx.x * 256 + threadIdx.x) >> 6;
    int lane = threadIdx.x & 63;
    if (wid >= BB * NF) return;
    const float a1 = 0.96f;
    const float a2 = a1 * a1;
    const float a4 = a2 * a2;
    const float a8 = a4 * a4;
    const float a16 = a8 * a8;
    const float a32 = a16 * a16;
    const float ss = 0.04f;
    float al1 = powf(a1, (float)(lane + 1));
    float carry = 0.0f;
    const float* row = X + wid * TOUT;
    float* mrow = M + wid * TOUT;

    for (int c = 0; c < TOUT; c += 64) {
        int t = c + lane;
        float v = (t < TOUT) ? row[t] : 0.0f;
        float y = ss * v;
        float u;
        u = __shfl_up(y, 1, 64);  if (lane >= 1)  y = fmaf(a1, u, y);
        u = __shfl_up(y, 2, 64);  if (lane >= 2)  y = fmaf(a2, u, y);
        u = __shfl_up(y, 4, 64);  if (lane >= 4)  y = fmaf(a4, u, y);
        u = __shfl_up(y, 8, 64);  if (lane >= 8)  y = fmaf(a8, u, y);
        u = __shfl_up(y, 16, 64); if (lane >= 16) y = fmaf(a16, u, y);
        u = __shfl_up(y, 32, 64); if (lane >= 32) y = fmaf(a32, u, y);
        y = fmaf(al1, carry, y);
        carry = __shfl(y, 63, 64);
        if (t < TOUT) mrow[t] = y;
    }
}

// ---------- GRU controller + PCEN via MFMA (C-layout gates) ----------
__global__ __launch_bounds__(256) void pcen_ctrl_mfma(
    const float* __restrict__ X, const float* __restrict__ M,
    const float* __restrict__ w_ih, const float* __restrict__ w_hh,
    const float* __restrict__ b_ih, const float* __restrict__ b_hh,
    const float* __restrict__ hw1, const float* __restrict__ hb1,
    const float* __restrict__ hw2, const float* __restrict__ hb2,
    float* __restrict__ out)
{
    __shared__ f16 s_whhA[96 * 40];
    __shared__ f16 s_w1A[32 * 40];
    __shared__ __align__(16) float4 s_A1[32];
    __shared__ __align__(16) float4 s_A2[32];
    __shared__ float s_hb1[32];
    __shared__ float s_hw2[64];
    __shared__ float s_hb2[2];
    __shared__ f16 sh1[4][16 * 40];
    __shared__ f16 sh2[4][16 * 40];
    __shared__ float sxc[4][16], sxp[4][16], smv[4][16];

    int tid = threadIdx.x;
    for (int i = tid; i < 96 * 32; i += 256) {
        int m = i >> 5, k = i & 31;
        s_whhA[m * 40 + k] = (f16)w_hh[i];
    }
    for (int i = tid; i < 32 * 32; i += 256) {
        int m = i >> 5, k = i & 31;
        s_w1A[m * 40 + k] = (f16)hw1[i];
    }
    if (tid < 32) {
        int j = tid;
        s_A1[j] = make_float4(w_ih[j], b_ih[j] + b_hh[j],
                              w_ih[32 + j], b_ih[32 + j] + b_hh[32 + j]);
        s_A2[j] = make_float4(w_ih[64 + j], b_ih[64 + j], b_hh[64 + j], 0.0f);
        s_hb1[j] = hb1[j];
    }
    if (tid < 64) s_hw2[tid] = hw2[tid];
    if (tid < 2)  s_hb2[tid] = hb2[tid];
    __syncthreads();

    int wv = tid >> 6, lane = tid & 63;
    int c = lane & 15, q = lane >> 4;
    int instBase = blockIdx.x * 64 + wv * 16;

    if (lane < 16) {
        int idx = instBase + lane;
        int t = idx % TOUT;
        float xcv = X[idx];
        float xpv = (t == 0) ? xcv : X[idx - 1];
        sxc[wv][lane] = xcv;
        sxp[wv][lane] = xpv;
        smv[wv][lane] = M[idx];
    }
    float xp = sxp[wv][c];
    float xc = sxc[wv][c];
    float mv = smv[wv][c];

    float h1v[8];
#pragma unroll
    for (int jj = 0; jj < 8; ++jj) {
        int j = (jj < 4) ? (4 * q + jj) : (16 + 4 * q + (jj - 4));
        float4 a1 = s_A1[j];
        float4 a2 = s_A2[j];
        float r = sigm(fmaf(xp, a1.x, a1.y));
        float z = sigm(fmaf(xp, a1.z, a1.w));
        float n = tanh_fast(fmaf(xp, a2.x, a2.y) + r * a2.z);
        h1v[jj] = (1.0f - z) * n;
    }

    {
        half4v lo = {(f16)h1v[0], (f16)h1v[1], (f16)h1v[2], (f16)h1v[3]};
        half4v hi = {(f16)h1v[4], (f16)h1v[5], (f16)h1v[6], (f16)h1v[7]};
        *(half4v*)(&sh1[wv][c * 40 + 4 * q]) = lo;
        *(half4v*)(&sh1[wv][c * 40 + 16 + 4 * q]) = hi;
    }

    float4v acc[6];
    {
        half8v bf = *(const half8v*)(&sh1[wv][c * 40 + 8 * q]);
#pragma unroll
        for (int t = 0; t < 6; ++t) {
            half8v af = *(const half8v*)(&s_whhA[(16 * t + c) * 40 + 8 * q]);
            acc[t] = __builtin_amdgcn_mfma_f32_16x16x32_f16(af, bf, (float4v){0.f,0.f,0.f,0.f}, 0, 0, 0);
        }
    }

    float h2v[8];
#pragma unroll
    for (int jj = 0; jj < 8; ++jj) {
        int j = (jj < 4) ? (4 * q + jj) : (16 + 4 * q + (jj - 4));
        int reg = jj & 3;
        float accR = (jj < 4) ? acc[0][reg] : acc[1][reg];
        float accZ = (jj < 4) ? acc[2][reg] : acc[3][reg];
        float accN = (jj < 4) ? acc[4][reg] : acc[5][reg];
        float4 a1 = s_A1[j];
        float4 a2 = s_A2[j];
        float r = sigm(fmaf(xc, a1.x, a1.y) + accR);
        float z = sigm(fmaf(xc, a1.z, a1.w) + accZ);
        float gn = accN + a2.z;
        float n = tanh_fast(fmaf(xc, a2.x, a2.y) + r * gn);
        h2v[jj] = fmaf(z, h1v[jj] - n, n);
    }

    {
        half4v lo = {(f16)h2v[0], (f16)h2v[1], (f16)h2v[2], (f16)h2v[3]};
        half4v hi = {(f16)h2v[4], (f16)h2v[5], (f16)h2v[6], (f16)h2v[7]};
        *(half4v*)(&sh2[wv][c * 40 + 4 * q]) = lo;
        *(half4v*)(&sh2[wv][c * 40 + 16 + 4 * q]) = hi;
    }

    float4v hacc[2];
    {
        half8v bf = *(const half8v*)(&sh2[wv][c * 40 + 8 * q]);
#pragma unroll
        for (int t = 0; t < 2; ++t) {
            half8v af = *(const half8v*)(&s_w1A[(16 * t + c) * 40 + 8 * q]);
            hacc[t] = __builtin_amdgcn_mfma_f32_16x16x32_f16(af, bf, (float4v){0.f,0.f,0.f,0.f}, 0, 0, 0);
        }
    }

    float p0 = 0.f, p1 = 0.f;
#pragma unroll
    for (int jj = 0; jj < 8; ++jj) {
        int i = (jj < 4) ? (4 * q + jj) : (16 + 4 * q + (jj - 4));
        int reg = jj & 3;
        float hv = (jj < 4) ? hacc[0][reg] : hacc[1][reg];
        hv = fmaxf(hv + s_hb1[i], 0.0f);
        p0 = fmaf(hv, s_hw2[i], p0);
        p1 = fmaf(hv, s_hw2[32 + i], p1);
    }
    p0 += __shfl_xor(p0, 16);
    p0 += __shfl_xor(p0, 32);
    p1 += __shfl_xor(p1, 16);
    p1 += __shfl_xor(p1, 32);

    float alpha = sigm(p0 + s_hb2[0]);
    float rr = fmaf(0.8f, sigm(p1 + s_hb2[1]), 0.2f);
    float md = __expf(alpha * __logf(mv + 1e-6f));
    float bse = xc / md + 2.0f;
    float val = __expf(rr * __logf(bse)) - __expf(rr * 0.69314718056f);
    if (lane < 16)
        out[instBase + lane] = val;
}

extern "C" void kernel_launch(void* const* d_in, const int* in_sizes, int n_in,
                              void* d_out, int out_size, void* d_ws, size_t ws_size,
                              hipStream_t stream) {
    const float* x    = (const float*)d_in[0];
    const float* cf   = (const float*)d_in[1];
    const float* bw   = (const float*)d_in[2];
    const float* pw   = (const float*)d_in[3];
    const float* w_ih = (const float*)d_in[4];
    const float* w_hh = (const float*)d_in[5];
    const float* b_ih = (const float*)d_in[6];
    const float* b_hh = (const float*)d_in[7];
    const float* hw1  = (const float*)d_in[8];
    const float* hb1  = (const float*)d_in[9];
    const float* hw2  = (const float*)d_in[10];
    const float* hb2  = (const float*)d_in[11];
    float* out = (float*)d_out;

    // tier: batches per conv slice, by ws capacity (ws_size constant -> graph-safe)
    const size_t xb_b = (size_t)BB * LST * 2;
    const size_t ag_b = (size_t)80 * AST * 2;
    const size_t xm_b = (size_t)2 * BB * NF * TOUT * 4;
    size_t fixed = xb_b + ag_b + xm_b;
    size_t e_per_batch = (size_t)NF * LL * 2;
    int nb;
    if (ws_size >= fixed + 8 * e_per_batch)      nb = 8;
    else if (ws_size >= fixed + 2 * e_per_batch) nb = 2;
    else                                         nb = 1;
    int nslice = BB / nb;

    f16* xb   = (f16*)d_ws;                     // [BB][LST]
    f16* Ag   = xb + (size_t)BB * LST;          // [80][AST]
    f16* ebuf = Ag + (size_t)80 * AST;          // [nb][NF][LL]
    float* Xf = (float*)(ebuf + (size_t)nb * NF * LL);
    float* Mf = Xf + (size_t)BB * NF * TOUT;

    prep_all<<<dim3(NCONVB + 80), dim3(256), 0, stream>>>(x, cf, bw, xb, Ag);

    for (int sl = 0; sl < nslice; ++sl) {
        conv_mfma<<<dim3(NCHUNKC, nb), dim3(256), 0, stream>>>(
            xb + (size_t)sl * nb * LST, Ag, ebuf);
        pool_kernel<<<dim3(NCHUNKP, NF, nb), dim3(256), 0, stream>>>(
            ebuf, pw, Xf + (size_t)sl * nb * NF * TOUT);
    }

    pcen_scan_kernel<<<dim3((BB * NF * 64) / 256), dim3(256), 0, stream>>>(Xf, Mf);
    pcen_ctrl_mfma<<<dim3((BB * NF * TOUT) / 64), dim3(256), 0, stream>>>(
        Xf, Mf, w_ih, w_hh, b_ih, b_hh, hw1, hb1, hw2, hb2, out);
}

// Round 8
// 260.730 us; speedup vs baseline: 1.1944x; 1.1944x over previous
//
#include <hip/hip_runtime.h>
#include <math.h>

#define NF 40
#define FS 401
#define AST 424            // A row stride (f16), 848B, 16B-aligned rows
#define PSTRIDE 160
#define BB 8
#define LL 160000
#define PADL 256
#define LST 161024         // PADL + LL + 768 pad; multiple of 256
#define TOUT 1000
#define NTILE 512          // conv positions per block (4 waves x 128)
#define NCHUNKC 313        // 313*512 = 160256 >= 160000
#define ROWCH 121          // slab chunk stride per row; 121 % 8 == 1
#define ROWST (ROWCH*8)    // 968 f16 per row
#define EROW 520           // e-LDS row stride (f16)
#define TCP 16             // frames per pool block
#define NCHUNKP 63
#define NCONVB 5032        // BB*LST/256 exactly

typedef __attribute__((ext_vector_type(8))) _Float16 half8v;
typedef __attribute__((ext_vector_type(4))) _Float16 half4v;
typedef __attribute__((ext_vector_type(4))) float float4v;
typedef _Float16 f16;

__device__ __forceinline__ float sigm(float x) { return 1.0f / (1.0f + __expf(-x)); }
__device__ __forceinline__ float tanh_fast(float x) { return 1.0f - 2.0f / (__expf(2.0f * x) + 1.0f); }

// ---------- prep (single dispatch): x->f16 padded, and Gabor filters ----------
__global__ __launch_bounds__(256) void prep_all(
    const float* __restrict__ x, const float* __restrict__ cf_,
    const float* __restrict__ bw_, f16* __restrict__ xb, f16* __restrict__ Ag)
{
    int blk = blockIdx.x;
    if (blk < NCONVB) {
        int i = blk * 256 + threadIdx.x;
        int b = i / LST, o = i % LST;
        float v = 0.0f;
        if (o >= PADL && o < PADL + LL) v = x[b * LL + (o - PADL)];
        xb[i] = (f16)v;
        return;
    }
    const float PI_F = 3.14159265358979323846f;
    int row = blk - NCONVB;         // 0..79
    int f = row >> 1, comp = row & 1;
    float Z = sqrtf(2.0f * logf(2.0f)) / PI_F;
    float cf = fminf(fmaxf(cf_[f], 0.0f), PI_F);
    float bw = fminf(fmaxf(bw_[f], 4.0f * Z), 401.0f * Z);
    float denom = 1.0f / (sqrtf(2.0f * PI_F) * bw);
    float inv2 = 1.0f / (2.0f * bw * bw);
    for (int k = threadIdx.x; k < AST; k += 256) {
        float v = 0.0f;
        if (k < FS) {
            float t = (float)(k - 200);
            float g = denom * expf(-(t * t) * inv2);
            float sv, cv;
            sincosf(cf * t, &sv, &cv);
            v = comp ? g * sv : g * cv;
        }
        Ag[row * AST + k] = (f16)v;
    }
}

// ---------- conv via MFMA: N=128/wave + Toeplitz rotation + coalesced epilogue ----------
__global__ __launch_bounds__(256, 2) void conv_mfma(
    const f16* __restrict__ xb,    // padded [nb][LST]
    const f16* __restrict__ Ag,    // [80][AST]
    f16* __restrict__ eb)          // [nb][NF][LL]
{
    // overlay: slab (8*ROWST f16 = 15488 B) during K-loop, e-tile (40*EROW f16 = 41600 B) after
    __shared__ __align__(16) unsigned char smem[40 * EROW * 2];
    f16* slab = (f16*)smem;
    f16* eL   = (f16*)smem;

    int chunk = blockIdx.x;
    int bi = blockIdx.y;
    int p0 = chunk * NTILE;
    int pbase = PADL + p0 - 200;              // ≡ 0 (mod 8)
    const f16* xs = xb + (size_t)bi * LST;
    int tid = threadIdx.x;

    // build 8-shifted-row slab: 8 rows x 120 chunks (columns 0..958 covered)
    for (int sc = tid; sc < 8 * 120; sc += 256) {
        int r = sc / 120, m = sc - r * 120;
        int s0 = pbase + 8 * m + (r & ~1);
        const uint* gp = (const uint*)(xs + s0);
        uint v0 = gp[0], v1 = gp[1], v2 = gp[2], v3 = gp[3], v4 = gp[4];
        if (r & 1) {
            v0 = __builtin_amdgcn_alignbyte(v1, v0, 2);
            v1 = __builtin_amdgcn_alignbyte(v2, v1, 2);
            v2 = __builtin_amdgcn_alignbyte(v3, v2, 2);
            v3 = __builtin_amdgcn_alignbyte(v4, v3, 2);
        }
        *(uint4*)(&slab[r * ROWST + 8 * m]) = make_uint4(v0, v1, v2, v3);
    }
    __syncthreads();

    int wv = tid >> 6, lane = tid & 63, q = lane >> 4, l15 = lane & 15;

    float4v acc[5][8];
#pragma unroll
    for (int t = 0; t < 5; ++t)
#pragma unroll
        for (int s = 0; s < 8; ++s)
            acc[t][s] = (float4v){0.f, 0.f, 0.f, 0.f};

    const f16* aP[5];
    const f16* bPtr[10];
#pragma unroll
    for (int t = 0; t < 5; ++t) aP[t] = Ag + (16 * t + l15) * AST + 8 * q;
#pragma unroll
    for (int s = 0; s < 10; ++s) {
        int pos = 128 * wv + 16 * s + l15;    // up to 543
        bPtr[s] = slab + (pos & 7) * ROWST + 8 * ((pos >> 3) + q);
    }

    half8v bf[8];
#pragma unroll
    for (int s = 0; s < 8; ++s) bf[s] = *(const half8v*)(bPtr[s]);

#pragma unroll
    for (int kk = 0; kk < 13; ++kk) {
        int k = 32 * kk;
        half8v af[5];
#pragma unroll
        for (int t = 0; t < 5; ++t) af[t] = *(const half8v*)(aP[t] + k);
        half8v nb0, nb1;
        if (kk < 12) {
            nb0 = *(const half8v*)(bPtr[8] + k);
            nb1 = *(const half8v*)(bPtr[9] + k);
        }
#pragma unroll
        for (int t = 0; t < 5; ++t)
#pragma unroll
            for (int s = 0; s < 8; ++s)
                acc[t][s] = __builtin_amdgcn_mfma_f32_16x16x32_f16(af[t], bf[s], acc[t][s], 0, 0, 0);
        if (kk < 12) {
#pragma unroll
            for (int s = 0; s < 6; ++s) bf[s] = bf[s + 2];
            bf[6] = nb0; bf[7] = nb1;
        }
    }

    __syncthreads();   // slab dead; eL overlays

    // energies -> LDS e-tile [40][EROW]
#pragma unroll
    for (int t = 0; t < 5; ++t) {
        int f0 = 8 * t + 2 * q;
#pragma unroll
        for (int s = 0; s < 8; ++s) {
            float4v a = acc[t][s];
            int pl = 128 * wv + 16 * s + l15;
            eL[f0 * EROW + pl] = (f16)(a.x * a.x + a.y * a.y);
            eL[(f0 + 1) * EROW + pl] = (f16)(a.z * a.z + a.w * a.w);
        }
    }
    __syncthreads();

    // coalesced store: 40 rows x 1024 B
    f16* ebb = eb + (size_t)bi * NF * LL;
#pragma unroll
    for (int it = 0; it < 10; ++it) {
        int idx = it * 256 + tid;
        int row = idx >> 6;
        int off = (idx & 63) * 8;
        if (p0 + off < LL) {
            uint4 v = *(const uint4*)(&eL[row * EROW + off]);
            *(uint4*)(&ebb[row * LL + p0 + off]) = v;
        }
    }
}

// ---------- Gaussian pooling: X[bi][f][tau] ----------
__global__ __launch_bounds__(256) void pool_kernel(
    const f16* __restrict__ eb, const float* __restrict__ pw_, float* __restrict__ Xout)
{
    __shared__ float ys[2816];
    __shared__ float win[416];
    int chunk = blockIdx.x;
    int f = blockIdx.y;
    int bi = blockIdx.z;
    int tau0 = chunk * TCP;
    int start = tau0 * PSTRIDE - 200;
    int tid = threadIdx.x;

    float pw = fminf(fmaxf(pw_[f], 2.0f / 401.0f), 0.5f);
    float invpw = 1.0f / pw;
    for (int k = tid; k < 416; k += 256) {
        float w = 0.0f;
        if (k < FS) {
            float tt = (float)k * (1.0f / 400.0f) - 0.5f;
            float u = tt * invpw;
            w = expf(-0.5f * u * u);
        }
        win[k] = w;
    }
    const f16* erow = eb + ((size_t)bi * NF + f) * LL;
    if (start >= 0 && start + 2816 <= LL) {
        for (int j = tid; j < 352; j += 256) {
            half8v v = *(const half8v*)(erow + start + 8 * j);
#pragma unroll
            for (int i = 0; i < 8; ++i) ys[8 * j + i] = (float)v[i];
        }
    } else {
        for (int j = tid; j < 2816; j += 256) {
            int p = start + j;
            ys[j] = (p >= 0 && p < LL) ? (float)erow[p] : 0.0f;
        }
    }
    __syncthreads();

    int ft = tid >> 4, l16 = tid & 15;
    float acc = 0.0f;
    int yo = ft * PSTRIDE;
    for (int kw = l16; kw < FS; kw += 16)
        acc += ys[yo + kw] * win[kw];
#pragma unroll
    for (int off = 8; off > 0; off >>= 1)
        acc += __shfl_down(acc, off, 16);
    int tau = tau0 + ft;
    if (l16 == 0 && tau < TOUT)
        Xout[((size_t)bi * NF + f) * TOUT + tau] = acc;
}

// ---------- PCEN smoother M via wave-per-bin decayed scan ----------
__global__ __launch_bounds__(256) void pcen_scan_kernel(
    const float* __restrict__ X, float* __restrict__ M)
{
    int wid = (blockIdx.x * 256 + threadIdx.x) >> 6;
    int lane = threadIdx.x & 63;
    if (wid >= BB * NF) return;
    const float a1 = 0.96f;
    const float a2 = a1 * a1;
    const float a4 = a2 * a2;
    const float a8 = a4 * a4;
    const float a16 = a8 * a8;
    const float a32 = a16 * a16;
    const float ss = 0.04f;
    float al1 = powf(a1, (float)(lane + 1));
    float carry = 0.0f;
    const float* row = X + wid * TOUT;
    float* mrow = M + wid * TOUT;

    for (int c = 0; c < TOUT; c += 64) {
        int t = c + lane;
        float v = (t < TOUT) ? row[t] : 0.0f;
        float y = ss * v;
        float u;
        u = __shfl_up(y, 1, 64);  if (lane >= 1)  y = fmaf(a1, u, y);
        u = __shfl_up(y, 2, 64);  if (lane >= 2)  y = fmaf(a2, u, y);
        u = __shfl_up(y, 4, 64);  if (lane >= 4)  y = fmaf(a4, u, y);
        u = __shfl_up(y, 8, 64);  if (lane >= 8)  y = fmaf(a8, u, y);
        u = __shfl_up(y, 16, 64); if (lane >= 16) y = fmaf(a16, u, y);
        u = __shfl_up(y, 32, 64); if (lane >= 32) y = fmaf(a32, u, y);
        y = fmaf(al1, carry, y);
        carry = __shfl(y, 63, 64);
        if (t < TOUT) mrow[t] = y;
    }
}

// ---------- GRU controller + PCEN via MFMA (C-layout gates) ----------
__global__ __launch_bounds__(256) void pcen_ctrl_mfma(
    const float* __restrict__ X, const float* __restrict__ M,
    const float* __restrict__ w_ih, const float* __restrict__ w_hh,
    const float* __restrict__ b_ih, const float* __restrict__ b_hh,
    const float* __restrict__ hw1, const float* __restrict__ hb1,
    const float* __restrict__ hw2, const float* __restrict__ hb2,
    float* __restrict__ out)
{
    __shared__ f16 s_whhA[96 * 40];
    __shared__ f16 s_w1A[32 * 40];
    __shared__ __align__(16) float4 s_A1[32];
    __shared__ __align__(16) float4 s_A2[32];
    __shared__ float s_hb1[32];
    __shared__ float s_hw2[64];
    __shared__ float s_hb2[2];
    __shared__ f16 sh1[4][16 * 40];
    __shared__ f16 sh2[4][16 * 40];
    __shared__ float sxc[4][16], sxp[4][16], smv[4][16];

    int tid = threadIdx.x;
    for (int i = tid; i < 96 * 32; i += 256) {
        int m = i >> 5, k = i & 31;
        s_whhA[m * 40 + k] = (f16)w_hh[i];
    }
    for (int i = tid; i < 32 * 32; i += 256) {
        int m = i >> 5, k = i & 31;
        s_w1A[m * 40 + k] = (f16)hw1[i];
    }
    if (tid < 32) {
        int j = tid;
        s_A1[j] = make_float4(w_ih[j], b_ih[j] + b_hh[j],
                              w_ih[32 + j], b_ih[32 + j] + b_hh[32 + j]);
        s_A2[j] = make_float4(w_ih[64 + j], b_ih[64 + j], b_hh[64 + j], 0.0f);
        s_hb1[j] = hb1[j];
    }
    if (tid < 64) s_hw2[tid] = hw2[tid];
    if (tid < 2)  s_hb2[tid] = hb2[tid];
    __syncthreads();

    int wv = tid >> 6, lane = tid & 63;
    int c = lane & 15, q = lane >> 4;
    int instBase = blockIdx.x * 64 + wv * 16;

    if (lane < 16) {
        int idx = instBase + lane;
        int t = idx % TOUT;
        float xcv = X[idx];
        float xpv = (t == 0) ? xcv : X[idx - 1];
        sxc[wv][lane] = xcv;
        sxp[wv][lane] = xpv;
        smv[wv][lane] = M[idx];
    }
    float xp = sxp[wv][c];
    float xc = sxc[wv][c];
    float mv = smv[wv][c];

    float h1v[8];
#pragma unroll
    for (int jj = 0; jj < 8; ++jj) {
        int j = (jj < 4) ? (4 * q + jj) : (16 + 4 * q + (jj - 4));
        float4 a1 = s_A1[j];
        float4 a2 = s_A2[j];
        float r = sigm(fmaf(xp, a1.x, a1.y));
        float z = sigm(fmaf(xp, a1.z, a1.w));
        float n = tanh_fast(fmaf(xp, a2.x, a2.y) + r * a2.z);
        h1v[jj] = (1.0f - z) * n;
    }

    {
        half4v lo = {(f16)h1v[0], (f16)h1v[1], (f16)h1v[2], (f16)h1v[3]};
        half4v hi = {(f16)h1v[4], (f16)h1v[5], (f16)h1v[6], (f16)h1v[7]};
        *(half4v*)(&sh1[wv][c * 40 + 4 * q]) = lo;
        *(half4v*)(&sh1[wv][c * 40 + 16 + 4 * q]) = hi;
    }

    float4v acc[6];
    {
        half8v bf = *(const half8v*)(&sh1[wv][c * 40 + 8 * q]);
#pragma unroll
        for (int t = 0; t < 6; ++t) {
            half8v af = *(const half8v*)(&s_whhA[(16 * t + c) * 40 + 8 * q]);
            acc[t] = __builtin_amdgcn_mfma_f32_16x16x32_f16(af, bf, (float4v){0.f,0.f,0.f,0.f}, 0, 0, 0);
        }
    }

    float h2v[8];
#pragma unroll
    for (int jj = 0; jj < 8; ++jj) {
        int j = (jj < 4) ? (4 * q + jj) : (16 + 4 * q + (jj - 4));
        int reg = jj & 3;
        float accR = (jj < 4) ? acc[0][reg] : acc[1][reg];
        float accZ = (jj < 4) ? acc[2][reg] : acc[3][reg];
        float accN = (jj < 4) ? acc[4][reg] : acc[5][reg];
        float4 a1 = s_A1[j];
        float4 a2 = s_A2[j];
        float r = sigm(fmaf(xc, a1.x, a1.y) + accR);
        float z = sigm(fmaf(xc, a1.z, a1.w) + accZ);
        float gn = accN + a2.z;
        float n = tanh_fast(fmaf(xc, a2.x, a2.y) + r * gn);
        h2v[jj] = fmaf(z, h1v[jj] - n, n);
    }

    {
        half4v lo = {(f16)h2v[0], (f16)h2v[1], (f16)h2v[2], (f16)h2v[3]};
        half4v hi = {(f16)h2v[4], (f16)h2v[5], (f16)h2v[6], (f16)h2v[7]};
        *(half4v*)(&sh2[wv][c * 40 + 4 * q]) = lo;
        *(half4v*)(&sh2[wv][c * 40 + 16 + 4 * q]) = hi;
    }

    float4v hacc[2];
    {
        half8v bf = *(const half8v*)(&sh2[wv][c * 40 + 8 * q]);
#pragma unroll
        for (int t = 0; t < 2; ++t) {
            half8v af = *(const half8v*)(&s_w1A[(16 * t + c) * 40 + 8 * q]);
            hacc[t] = __builtin_amdgcn_mfma_f32_16x16x32_f16(af, bf, (float4v){0.f,0.f,0.f,0.f}, 0, 0, 0);
        }
    }

    float p0 = 0.f, p1 = 0.f;
#pragma unroll
    for (int jj = 0; jj < 8; ++jj) {
        int i = (jj < 4) ? (4 * q + jj) : (16 + 4 * q + (jj - 4));
        int reg = jj & 3;
        float hv = (jj < 4) ? hacc[0][reg] : hacc[1][reg];
        hv = fmaxf(hv + s_hb1[i], 0.0f);
        p0 = fmaf(hv, s_hw2[i], p0);
        p1 = fmaf(hv, s_hw2[32 + i], p1);
    }
    p0 += __shfl_xor(p0, 16);
    p0 += __shfl_xor(p0, 32);
    p1 += __shfl_xor(p1, 16);
    p1 += __shfl_xor(p1, 32);

    float alpha = sigm(p0 + s_hb2[0]);
    float rr = fmaf(0.8f, sigm(p1 + s_hb2[1]), 0.2f);
    float md = __expf(alpha * __logf(mv + 1e-6f));
    float bse = xc / md + 2.0f;
    float val = __expf(rr * __logf(bse)) - __expf(rr * 0.69314718056f);
    if (lane < 16)
        out[instBase + lane] = val;
}

extern "C" void kernel_launch(void* const* d_in, const int* in_sizes, int n_in,
                              void* d_out, int out_size, void* d_ws, size_t ws_size,
                              hipStream_t stream) {
    const float* x    = (const float*)d_in[0];
    const float* cf   = (const float*)d_in[1];
    const float* bw   = (const float*)d_in[2];
    const float* pw   = (const float*)d_in[3];
    const float* w_ih = (const float*)d_in[4];
    const float* w_hh = (const float*)d_in[5];
    const float* b_ih = (const float*)d_in[6];
    const float* b_hh = (const float*)d_in[7];
    const float* hw1  = (const float*)d_in[8];
    const float* hb1  = (const float*)d_in[9];
    const float* hw2  = (const float*)d_in[10];
    const float* hb2  = (const float*)d_in[11];
    float* out = (float*)d_out;

    // tier: batches per conv slice, by ws capacity (ws_size constant -> graph-safe)
    const size_t xb_b = (size_t)BB * LST * 2;
    const size_t ag_b = (size_t)80 * AST * 2;
    const size_t xm_b = (size_t)2 * BB * NF * TOUT * 4;
    size_t fixed = xb_b + ag_b + xm_b;
    size_t e_per_batch = (size_t)NF * LL * 2;
    int nb;
    if (ws_size >= fixed + 8 * e_per_batch)      nb = 8;
    else if (ws_size >= fixed + 2 * e_per_batch) nb = 2;
    else                                         nb = 1;
    int nslice = BB / nb;

    f16* xb   = (f16*)d_ws;                     // [BB][LST]
    f16* Ag   = xb + (size_t)BB * LST;          // [80][AST]
    f16* ebuf = Ag + (size_t)80 * AST;          // [nb][NF][LL]
    float* Xf = (float*)(ebuf + (size_t)nb * NF * LL);
    float* Mf = Xf + (size_t)BB * NF * TOUT;

    prep_all<<<dim3(NCONVB + 80), dim3(256), 0, stream>>>(x, cf, bw, xb, Ag);

    for (int sl = 0; sl < nslice; ++sl) {
        conv_mfma<<<dim3(NCHUNKC, nb), dim3(256), 0, stream>>>(
            xb + (size_t)sl * nb * LST, Ag, ebuf);
        pool_kernel<<<dim3(NCHUNKP, NF, nb), dim3(256), 0, stream>>>(
            ebuf, pw, Xf + (size_t)sl * nb * NF * TOUT);
    }

    pcen_scan_kernel<<<dim3((BB * NF * 64) / 256), dim3(256), 0, stream>>>(Xf, Mf);
    pcen_ctrl_mfma<<<dim3((BB * NF * TOUT) / 64), dim3(256), 0, stream>>>(
        Xf, Mf, w_ih, w_hh, b_ih, b_hh, hw1, hb1, hw2, hb2, out);
}